// Round 1
// baseline (5555.440 us; speedup 1.0000x reference)
//
#include <hip/hip_runtime.h>
#include <math.h>

#define LN_EPS 1e-5f
#define TP 32   // points per block in pce_kernel
#define TN 8    // nodes per block in node_kernel
#define TE 8    // edges per block in edge_kernel

// ---------------------------------------------------------------------------
// stats: sum(x_i), sum(x_i x_j) over rows of (P,3) -> 9 floats (atomicAdd)
// ---------------------------------------------------------------------------
__global__ __launch_bounds__(256) void stats_kernel(const float* __restrict__ x, int P,
                                                    float* __restrict__ stats) {
    int tid = blockIdx.x * blockDim.x + threadIdx.x;
    int stride = gridDim.x * blockDim.x;
    float s[9] = {0.f,0.f,0.f,0.f,0.f,0.f,0.f,0.f,0.f};
    for (int i = tid; i < P; i += stride) {
        float a = x[i*3+0], b = x[i*3+1], c = x[i*3+2];
        s[0]+=a; s[1]+=b; s[2]+=c;
        s[3]+=a*a; s[4]+=a*b; s[5]+=a*c;
        s[6]+=b*b; s[7]+=b*c; s[8]+=c*c;
    }
    #pragma unroll
    for (int j = 0; j < 9; j++) {
        float v = s[j];
        for (int off = 32; off > 0; off >>= 1) v += __shfl_down(v, off, 64);
        if ((threadIdx.x & 63) == 0) atomicAdd(&stats[j], v);
    }
}

// ---------------------------------------------------------------------------
// fold BN into W1/b1:  bn(x@W1+b1) = x@W1f + b1f   (exact: t linear in x)
// ---------------------------------------------------------------------------
__global__ void fold_bn_kernel(const float* __restrict__ stats,
                               const float* __restrict__ W1, const float* __restrict__ b1,
                               const float* __restrict__ g,  const float* __restrict__ b,
                               float Pinv,
                               float* __restrict__ W1f, float* __restrict__ b1f) {
    int c = threadIdx.x;
    float m0 = stats[0]*Pinv, m1 = stats[1]*Pinv, m2 = stats[2]*Pinv;
    float C00 = stats[3]*Pinv - m0*m0;
    float C01 = stats[4]*Pinv - m0*m1;
    float C02 = stats[5]*Pinv - m0*m2;
    float C11 = stats[6]*Pinv - m1*m1;
    float C12 = stats[7]*Pinv - m1*m2;
    float C22 = stats[8]*Pinv - m2*m2;
    float w0 = W1[c], w1 = W1[256+c], w2 = W1[512+c];
    float mean = m0*w0 + m1*w1 + m2*w2 + b1[c];
    float var  = C00*w0*w0 + C11*w1*w1 + C22*w2*w2
               + 2.f*(C01*w0*w1 + C02*w0*w2 + C12*w1*w2);
    float a = g[c] * rsqrtf(var + LN_EPS);
    W1f[c]     = w0*a;
    W1f[256+c] = w1*a;
    W1f[512+c] = w2*a;
    b1f[c] = (b1[c] - mean)*a + b[c];
}

// ---------------------------------------------------------------------------
// small C[r][c] = sum_j A[r*J+j] * B[j*256+c]   (grid = rows, block = 256)
// ---------------------------------------------------------------------------
__global__ void small_matmul_kernel(const float* __restrict__ A, const float* __restrict__ B,
                                    float* __restrict__ C, int J) {
    int r = blockIdx.x, c = threadIdx.x;
    const float* Ar = A + (size_t)r * J;
    float acc = 0.f;
    for (int j = 0; j < J; j++) acc += Ar[j] * B[j*256 + c];
    C[r*256 + c] = acc;
}

// ---------------------------------------------------------------------------
// constants: node_const = nf_b + sem_b@nf_W[0:256]
//            edge_const = ef_b + ep_b2@ef_W[256:512] + ea_b@ef_W[512:768] + epo_b@ef_W[768:1024]
// ---------------------------------------------------------------------------
__global__ void consts_kernel(const float* __restrict__ sem_b, const float* __restrict__ nf_W,
                              const float* __restrict__ nf_b,
                              const float* __restrict__ ep_b2, const float* __restrict__ ea_b,
                              const float* __restrict__ epo_b, const float* __restrict__ ef_W,
                              const float* __restrict__ ef_b,
                              float* __restrict__ node_const, float* __restrict__ edge_const) {
    int c = threadIdx.x;
    float nc = nf_b[c];
    for (int j = 0; j < 256; j++) nc += sem_b[j] * nf_W[j*256 + c];
    node_const[c] = nc;
    float ec = ef_b[c];
    for (int j = 0; j < 256; j++) ec += ep_b2[j] * ef_W[(256+j)*256 + c];
    for (int j = 0; j < 24;  j++) ec += ea_b[j]  * ef_W[(512+j)*256 + c];
    for (int j = 0; j < 9;   j++) ec += epo_b[j] * ef_W[(768+j)*256 + c];
    edge_const[c] = ec;
}

// ---------------------------------------------------------------------------
// point-cloud encoder: u = relu(x@W1f+b1f); y = relu(u@W2+b2); atomicMax scatter
// ---------------------------------------------------------------------------
__global__ __launch_bounds__(256) void pce_kernel(
    const float* __restrict__ x, const int* __restrict__ bidx,
    const float* __restrict__ W1f, const float* __restrict__ b1f,
    const float* __restrict__ W2,  const float* __restrict__ b2,
    float* __restrict__ seg, int P)
{
    __shared__ float xs[TP*3];
    __shared__ float u[TP][256];
    int tid = threadIdx.x;
    int base = blockIdx.x * TP;
    int np = min(TP, P - base);

    if (tid < np*3) xs[tid] = x[(size_t)base*3 + tid];
    __syncthreads();

    int c = tid;
    float w0 = W1f[c], w1 = W1f[256+c], w2 = W1f[512+c], bb = b1f[c];
    #pragma unroll
    for (int p = 0; p < TP; p++) {
        float v = 0.f;
        if (p < np) v = fmaxf(xs[p*3]*w0 + xs[p*3+1]*w1 + xs[p*3+2]*w2 + bb, 0.f);
        u[p][c] = v;
    }
    __syncthreads();

    float acc[TP];
    float bias = b2[c];
    #pragma unroll
    for (int p = 0; p < TP; p++) acc[p] = bias;

    for (int k4 = 0; k4 < 64; k4++) {
        int k = k4*4;
        float g0 = W2[(k+0)*256 + c];
        float g1 = W2[(k+1)*256 + c];
        float g2 = W2[(k+2)*256 + c];
        float g3 = W2[(k+3)*256 + c];
        #pragma unroll
        for (int p = 0; p < TP; p++) {
            float4 uv = *(const float4*)&u[p][k];
            acc[p] += uv.x*g0 + uv.y*g1 + uv.z*g2 + uv.w*g3;
        }
    }

    #pragma unroll
    for (int p = 0; p < TP; p++) {
        if (p < np) {
            float y = fmaxf(acc[p], 0.f);
            int node = bidx[base + p];
            atomicMax((unsigned int*)&seg[(size_t)node*256 + c], __float_as_uint(y));
        }
    }
}

// ---------------------------------------------------------------------------
// per-wave LN stats over a 256-wide LDS row (2 rows per wave, TN/TE = 8)
// ---------------------------------------------------------------------------
__device__ __forceinline__ void ln_reduce_8rows(const float (*rows)[256], float (*mr)[2],
                                                int tid) {
    int wave = tid >> 6, lane = tid & 63;
    #pragma unroll
    for (int t = 0; t < 2; t++) {
        int n = wave*2 + t;
        float v0 = rows[n][lane], v1 = rows[n][64+lane],
              v2 = rows[n][128+lane], v3 = rows[n][192+lane];
        float s = v0+v1+v2+v3;
        float q = v0*v0+v1*v1+v2*v2+v3*v3;
        for (int off = 32; off > 0; off >>= 1) {
            s += __shfl_down(s, off, 64);
            q += __shfl_down(q, off, 64);
        }
        if (lane == 0) {
            float mean = s * (1.f/256.f);
            float var  = q * (1.f/256.f) - mean*mean;
            mr[n][0] = mean;
            mr[n][1] = rsqrtf(var + LN_EPS);
        }
    }
}

// ---------------------------------------------------------------------------
// nodes: pre = x_sem@sem_comb + h_pos@nf_W[256:512] + h_aff@nf_W[512:768] + node_const
//        out = relu(LN(pre))
// ---------------------------------------------------------------------------
__global__ __launch_bounds__(256) void node_kernel(
    const float* __restrict__ x_sem, const float* __restrict__ h_pos,
    const float* __restrict__ h_aff,
    const float* __restrict__ sem_comb, const float* __restrict__ nf_W,
    const float* __restrict__ node_const,
    const float* __restrict__ ln_g, const float* __restrict__ ln_b,
    float* __restrict__ out, int N)
{
    __shared__ float cat[TN][1024];
    __shared__ float pre[TN][256];
    __shared__ float mr[TN][2];
    int tid = threadIdx.x;
    int base = blockIdx.x * TN;
    int nn = min(TN, N - base);

    for (int i = tid; i < TN*512; i += 256) {
        int n = i >> 9, k = i & 511;
        cat[n][k] = (n < nn) ? x_sem[(size_t)(base+n)*512 + k] : 0.f;
    }
    for (int i = tid; i < TN*256; i += 256) {
        int n = i >> 8, k = i & 255;
        cat[n][512+k] = (n < nn) ? h_pos[(size_t)(base+n)*256 + k] : 0.f;
        cat[n][768+k] = (n < nn) ? h_aff[(size_t)(base+n)*256 + k] : 0.f;
    }
    __syncthreads();

    int c = tid;
    float acc[TN];
    float cst = node_const[c];
    #pragma unroll
    for (int n = 0; n < TN; n++) acc[n] = cst;

    for (int k4 = 0; k4 < 128; k4++) {     // x_sem part, K=512
        int k = k4*4;
        float g0 = sem_comb[(k+0)*256+c], g1 = sem_comb[(k+1)*256+c],
              g2 = sem_comb[(k+2)*256+c], g3 = sem_comb[(k+3)*256+c];
        #pragma unroll
        for (int n = 0; n < TN; n++) {
            float4 uv = *(const float4*)&cat[n][k];
            acc[n] += uv.x*g0 + uv.y*g1 + uv.z*g2 + uv.w*g3;
        }
    }
    const float* Wp = nf_W + 256*256;
    for (int k4 = 0; k4 < 64; k4++) {      // h_pos part
        int k = k4*4;
        float g0 = Wp[(k+0)*256+c], g1 = Wp[(k+1)*256+c],
              g2 = Wp[(k+2)*256+c], g3 = Wp[(k+3)*256+c];
        #pragma unroll
        for (int n = 0; n < TN; n++) {
            float4 uv = *(const float4*)&cat[n][512+k];
            acc[n] += uv.x*g0 + uv.y*g1 + uv.z*g2 + uv.w*g3;
        }
    }
    const float* Wq = nf_W + 512*256;
    for (int k4 = 0; k4 < 64; k4++) {      // h_aff part
        int k = k4*4;
        float g0 = Wq[(k+0)*256+c], g1 = Wq[(k+1)*256+c],
              g2 = Wq[(k+2)*256+c], g3 = Wq[(k+3)*256+c];
        #pragma unroll
        for (int n = 0; n < TN; n++) {
            float4 uv = *(const float4*)&cat[n][768+k];
            acc[n] += uv.x*g0 + uv.y*g1 + uv.z*g2 + uv.w*g3;
        }
    }
    __syncthreads();
    #pragma unroll
    for (int n = 0; n < TN; n++) pre[n][c] = acc[n];
    __syncthreads();
    ln_reduce_8rows(pre, mr, tid);
    __syncthreads();

    float gc = ln_g[c], bc = ln_b[c];
    #pragma unroll
    for (int n = 0; n < TN; n++) {
        if (n < nn) {
            float y = (acc[n] - mr[n][0]) * mr[n][1] * gc + bc;
            out[(size_t)(base+n)*256 + c] = fmaxf(y, 0.f);
        }
    }
}

// ---------------------------------------------------------------------------
// edges: h1 = relu(LN(v@ep_W1+ep_b1)); pre = type_proj[t] + h1@param_comb
//        + anchor@anchor_comb + pose@pose_comb + edge_const; out = relu(LN(pre))
// ---------------------------------------------------------------------------
__global__ __launch_bounds__(256) void edge_kernel(
    const int* __restrict__ etype, const float* __restrict__ eparam,
    const float* __restrict__ eanchor, const float* __restrict__ epose,
    const float* __restrict__ ep_W1, const float* __restrict__ ep_b1,
    const float* __restrict__ ep_ln_g, const float* __restrict__ ep_ln_b,
    const float* __restrict__ type_proj, const float* __restrict__ param_comb,
    const float* __restrict__ anchor_comb, const float* __restrict__ pose_comb,
    const float* __restrict__ edge_const,
    const float* __restrict__ ln_g, const float* __restrict__ ln_b,
    float* __restrict__ out, int E)
{
    __shared__ float h1[TE][256];
    __shared__ float va[TE][5];
    __shared__ float an[TE*24];
    __shared__ float po[TE*9];
    __shared__ int   ty[TE];
    __shared__ float mr[TE][2];
    int tid = threadIdx.x;
    int base = blockIdx.x * TE;
    int ne = min(TE, E - base);

    if (tid < TE) {
        int e = tid;
        if (e < ne) {
            float d  = eparam[(size_t)(base+e)*3 + 0];
            float th = eparam[(size_t)(base+e)*3 + 1];
            float ph = eparam[(size_t)(base+e)*3 + 2];
            va[e][0] = fminf(fmaxf(d*10.f, -5.f), 5.f);
            va[e][1] = __sinf(th); va[e][2] = __cosf(th);
            va[e][3] = __sinf(ph); va[e][4] = __cosf(ph);
            ty[e] = etype[base+e];
        } else {
            va[e][0]=va[e][1]=va[e][2]=va[e][3]=va[e][4]=0.f; ty[e]=0;
        }
    }
    for (int i = tid; i < TE*24; i += 256) an[i] = (i < ne*24) ? eanchor[(size_t)base*24 + i] : 0.f;
    for (int i = tid; i < TE*9;  i += 256) po[i] = (i < ne*9)  ? epose[(size_t)base*9 + i]   : 0.f;
    __syncthreads();

    int c = tid;
    float t[TE];
    {
        float w0=ep_W1[c], w1=ep_W1[256+c], w2=ep_W1[512+c], w3=ep_W1[768+c], w4=ep_W1[1024+c];
        float bb = ep_b1[c];
        #pragma unroll
        for (int e = 0; e < TE; e++) {
            t[e] = va[e][0]*w0 + va[e][1]*w1 + va[e][2]*w2 + va[e][3]*w3 + va[e][4]*w4 + bb;
            h1[e][c] = t[e];
        }
    }
    __syncthreads();
    ln_reduce_8rows(h1, mr, tid);
    __syncthreads();
    {
        float gc = ep_ln_g[c], bc = ep_ln_b[c];
        #pragma unroll
        for (int e = 0; e < TE; e++)
            h1[e][c] = fmaxf((t[e] - mr[e][0]) * mr[e][1] * gc + bc, 0.f);
    }
    __syncthreads();

    float acc[TE];
    float cst = edge_const[c];
    #pragma unroll
    for (int e = 0; e < TE; e++) acc[e] = cst + type_proj[ty[e]*256 + c];

    for (int k4 = 0; k4 < 64; k4++) {
        int k = k4*4;
        float g0 = param_comb[(k+0)*256+c], g1 = param_comb[(k+1)*256+c],
              g2 = param_comb[(k+2)*256+c], g3 = param_comb[(k+3)*256+c];
        #pragma unroll
        for (int e = 0; e < TE; e++) {
            float4 uv = *(const float4*)&h1[e][k];
            acc[e] += uv.x*g0 + uv.y*g1 + uv.z*g2 + uv.w*g3;
        }
    }
    for (int k = 0; k < 24; k++) {
        float g0 = anchor_comb[k*256 + c];
        #pragma unroll
        for (int e = 0; e < TE; e++) acc[e] += an[e*24+k] * g0;
    }
    for (int k = 0; k < 9; k++) {
        float g0 = pose_comb[k*256 + c];
        #pragma unroll
        for (int e = 0; e < TE; e++) acc[e] += po[e*9+k] * g0;
    }
    __syncthreads();
    #pragma unroll
    for (int e = 0; e < TE; e++) h1[e][c] = acc[e];
    __syncthreads();
    ln_reduce_8rows(h1, mr, tid);
    __syncthreads();

    float gc = ln_g[c], bc = ln_b[c];
    #pragma unroll
    for (int e = 0; e < TE; e++) {
        if (e < ne) {
            float y = (acc[e] - mr[e][0]) * mr[e][1] * gc + bc;
            out[(size_t)(base+e)*256 + c] = fmaxf(y, 0.f);
        }
    }
}

// ---------------------------------------------------------------------------
extern "C" void kernel_launch(void* const* d_in, const int* in_sizes, int n_in,
                              void* d_out, int out_size, void* d_ws, size_t ws_size,
                              hipStream_t stream)
{
    const float* x_sem     = (const float*)d_in[0];
    const float* x_pos     = (const float*)d_in[1];
    const int*   pos_bidx  = (const int*)  d_in[2];
    const float* x_aff     = (const float*)d_in[3];
    const int*   aff_bidx  = (const int*)  d_in[4];
    const int*   edge_type = (const int*)  d_in[5];
    const float* edge_param  = (const float*)d_in[6];
    const float* edge_anchor = (const float*)d_in[7];
    const float* edge_pose   = (const float*)d_in[8];
    // d_in[9] = num_nodes (device scalar) — equals N by construction
    const float* sem_W  = (const float*)d_in[10];
    const float* sem_b  = (const float*)d_in[11];
    const float* pos_W1 = (const float*)d_in[12];
    const float* pos_b1 = (const float*)d_in[13];
    const float* pos_bn_g = (const float*)d_in[14];
    const float* pos_bn_b = (const float*)d_in[15];
    const float* pos_W2 = (const float*)d_in[16];
    const float* pos_b2 = (const float*)d_in[17];
    const float* aff_W1 = (const float*)d_in[18];
    const float* aff_b1 = (const float*)d_in[19];
    const float* aff_bn_g = (const float*)d_in[20];
    const float* aff_bn_b = (const float*)d_in[21];
    const float* aff_W2 = (const float*)d_in[22];
    const float* aff_b2 = (const float*)d_in[23];
    const float* nf_W   = (const float*)d_in[24];
    const float* nf_b   = (const float*)d_in[25];
    const float* nf_ln_g = (const float*)d_in[26];
    const float* nf_ln_b = (const float*)d_in[27];
    const float* et_emb = (const float*)d_in[28];
    const float* ep_W1  = (const float*)d_in[29];
    const float* ep_b1  = (const float*)d_in[30];
    const float* ep_ln_g = (const float*)d_in[31];
    const float* ep_ln_b = (const float*)d_in[32];
    const float* ep_W2  = (const float*)d_in[33];
    const float* ep_b2  = (const float*)d_in[34];
    const float* ea_W   = (const float*)d_in[35];
    const float* ea_b   = (const float*)d_in[36];
    const float* epo_W  = (const float*)d_in[37];
    const float* epo_b  = (const float*)d_in[38];
    const float* ef_W   = (const float*)d_in[39];
    const float* ef_b   = (const float*)d_in[40];
    const float* ef_ln_g = (const float*)d_in[41];
    const float* ef_ln_b = (const float*)d_in[42];

    int N = in_sizes[0] / 512;
    int P = in_sizes[1] / 3;
    int E = in_sizes[5];

    float* ws = (float*)d_ws;
    float* h_pos      = ws;                              // N*256
    float* h_aff      = h_pos + (size_t)N*256;           // N*256
    float* stats_pos  = h_aff + (size_t)N*256;           // 16
    float* stats_aff  = stats_pos + 16;                  // 16
    float* pos_W1f    = stats_aff + 16;                  // 768
    float* pos_b1f    = pos_W1f + 768;                   // 256
    float* aff_W1f    = pos_b1f + 256;                   // 768
    float* aff_b1f    = aff_W1f + 768;                   // 256
    float* sem_comb   = aff_b1f + 256;                   // 512*256
    float* param_comb = sem_comb + 512*256;              // 256*256
    float* anchor_comb= param_comb + 256*256;            // 24*256
    float* pose_comb  = anchor_comb + 24*256;            // 9*256
    float* type_proj  = pose_comb + 9*256;               // 7*256
    float* node_const = type_proj + 7*256;               // 256
    float* edge_const = node_const + 256;                // 256

    // zero atomicMax targets + stats (ws is poisoned 0xAA before every call)
    hipMemsetAsync(ws, 0, ((size_t)2*N*256 + 32) * sizeof(float), stream);

    stats_kernel<<<512, 256, 0, stream>>>(x_pos, P, stats_pos);
    stats_kernel<<<512, 256, 0, stream>>>(x_aff, P, stats_aff);
    fold_bn_kernel<<<1, 256, 0, stream>>>(stats_pos, pos_W1, pos_b1, pos_bn_g, pos_bn_b,
                                          1.f/(float)P, pos_W1f, pos_b1f);
    fold_bn_kernel<<<1, 256, 0, stream>>>(stats_aff, aff_W1, aff_b1, aff_bn_g, aff_bn_b,
                                          1.f/(float)P, aff_W1f, aff_b1f);

    small_matmul_kernel<<<512, 256, 0, stream>>>(sem_W,  nf_W,            sem_comb,   256);
    small_matmul_kernel<<<256, 256, 0, stream>>>(ep_W2,  ef_W + 256*256,  param_comb, 256);
    small_matmul_kernel<<<24,  256, 0, stream>>>(ea_W,   ef_W + 512*256,  anchor_comb,256);
    small_matmul_kernel<<<9,   256, 0, stream>>>(epo_W,  ef_W + 768*256,  pose_comb,  256);
    small_matmul_kernel<<<7,   256, 0, stream>>>(et_emb, ef_W,            type_proj,  256);
    consts_kernel<<<1, 256, 0, stream>>>(sem_b, nf_W, nf_b, ep_b2, ea_b, epo_b, ef_W, ef_b,
                                         node_const, edge_const);

    pce_kernel<<<(P + TP - 1)/TP, 256, 0, stream>>>(x_pos, pos_bidx, pos_W1f, pos_b1f,
                                                    pos_W2, pos_b2, h_pos, P);
    pce_kernel<<<(P + TP - 1)/TP, 256, 0, stream>>>(x_aff, aff_bidx, aff_W1f, aff_b1f,
                                                    aff_W2, aff_b2, h_aff, P);

    node_kernel<<<(N + TN - 1)/TN, 256, 0, stream>>>(x_sem, h_pos, h_aff, sem_comb, nf_W,
                                                     node_const, nf_ln_g, nf_ln_b,
                                                     (float*)d_out, N);
    edge_kernel<<<(E + TE - 1)/TE, 256, 0, stream>>>(edge_type, edge_param, edge_anchor, edge_pose,
                                                     ep_W1, ep_b1, ep_ln_g, ep_ln_b,
                                                     type_proj, param_comb, anchor_comb, pose_comb,
                                                     edge_const, ef_ln_g, ef_ln_b,
                                                     (float*)d_out + (size_t)N*256, E);
}

// Round 2
// 3690.513 us; speedup vs baseline: 1.5053x; 1.5053x over previous
//
#include <hip/hip_runtime.h>
#include <math.h>

#define LN_EPS 1e-5f
#define TN 8    // nodes per block in node_kernel
#define TE 8    // edges per block in edge_kernel

typedef __attribute__((ext_vector_type(8))) short short8;   // 8 bf16 = 4 VGPRs
typedef __attribute__((ext_vector_type(4))) float floatx4;  // MFMA C/D

__device__ __forceinline__ unsigned short f32_to_bf16_rne(float v) {
    unsigned int u = __float_as_uint(v);
    return (unsigned short)((u + 0x7FFFu + ((u >> 16) & 1u)) >> 16);
}

// ---------------------------------------------------------------------------
// stats: sum(x_i), sum(x_i x_j) over rows of (P,3) -> 9 floats (atomicAdd)
// ---------------------------------------------------------------------------
__global__ __launch_bounds__(256) void stats_kernel(const float* __restrict__ x, int P,
                                                    float* __restrict__ stats) {
    int tid = blockIdx.x * blockDim.x + threadIdx.x;
    int stride = gridDim.x * blockDim.x;
    float s[9] = {0.f,0.f,0.f,0.f,0.f,0.f,0.f,0.f,0.f};
    for (int i = tid; i < P; i += stride) {
        float a = x[i*3+0], b = x[i*3+1], c = x[i*3+2];
        s[0]+=a; s[1]+=b; s[2]+=c;
        s[3]+=a*a; s[4]+=a*b; s[5]+=a*c;
        s[6]+=b*b; s[7]+=b*c; s[8]+=c*c;
    }
    #pragma unroll
    for (int j = 0; j < 9; j++) {
        float v = s[j];
        for (int off = 32; off > 0; off >>= 1) v += __shfl_down(v, off, 64);
        if ((threadIdx.x & 63) == 0) atomicAdd(&stats[j], v);
    }
}

// ---------------------------------------------------------------------------
// fold BN into W1/b1:  bn(x@W1+b1) = x@W1f + b1f   (exact: t linear in x)
// ---------------------------------------------------------------------------
__global__ void fold_bn_kernel(const float* __restrict__ stats,
                               const float* __restrict__ W1, const float* __restrict__ b1,
                               const float* __restrict__ g,  const float* __restrict__ b,
                               float Pinv,
                               float* __restrict__ W1f, float* __restrict__ b1f) {
    int c = threadIdx.x;
    float m0 = stats[0]*Pinv, m1 = stats[1]*Pinv, m2 = stats[2]*Pinv;
    float C00 = stats[3]*Pinv - m0*m0;
    float C01 = stats[4]*Pinv - m0*m1;
    float C02 = stats[5]*Pinv - m0*m2;
    float C11 = stats[6]*Pinv - m1*m1;
    float C12 = stats[7]*Pinv - m1*m2;
    float C22 = stats[8]*Pinv - m2*m2;
    float w0 = W1[c], w1 = W1[256+c], w2 = W1[512+c];
    float mean = m0*w0 + m1*w1 + m2*w2 + b1[c];
    float var  = C00*w0*w0 + C11*w1*w1 + C22*w2*w2
               + 2.f*(C01*w0*w1 + C02*w0*w2 + C12*w1*w2);
    float a = g[c] * rsqrtf(var + LN_EPS);
    W1f[c]     = w0*a;
    W1f[256+c] = w1*a;
    W1f[512+c] = w2*a;
    b1f[c] = (b1[c] - mean)*a + b[c];
}

// ---------------------------------------------------------------------------
// transpose + bf16-cast a 256x256 weight: Wt[n][k] = bf16(W[k][n])
// ---------------------------------------------------------------------------
__global__ void convert_w2_kernel(const float* __restrict__ W,
                                  unsigned short* __restrict__ Wt) {
    int n = blockIdx.x, k = threadIdx.x;
    Wt[n*256 + k] = f32_to_bf16_rne(W[k*256 + n]);
}

// ---------------------------------------------------------------------------
// small C[r][c] = sum_j A[r*J+j] * B[j*256+c]   (grid = rows, block = 256)
// ---------------------------------------------------------------------------
__global__ void small_matmul_kernel(const float* __restrict__ A, const float* __restrict__ B,
                                    float* __restrict__ C, int J) {
    int r = blockIdx.x, c = threadIdx.x;
    const float* Ar = A + (size_t)r * J;
    float acc = 0.f;
    for (int j = 0; j < J; j++) acc += Ar[j] * B[j*256 + c];
    C[r*256 + c] = acc;
}

// ---------------------------------------------------------------------------
// constants: node_const = nf_b + sem_b@nf_W[0:256]
//            edge_const = ef_b + ep_b2@ef_W[256:512] + ea_b@ef_W[512:768] + epo_b@ef_W[768:1024]
// ---------------------------------------------------------------------------
__global__ void consts_kernel(const float* __restrict__ sem_b, const float* __restrict__ nf_W,
                              const float* __restrict__ nf_b,
                              const float* __restrict__ ep_b2, const float* __restrict__ ea_b,
                              const float* __restrict__ epo_b, const float* __restrict__ ef_W,
                              const float* __restrict__ ef_b,
                              float* __restrict__ node_const, float* __restrict__ edge_const) {
    int c = threadIdx.x;
    float nc = nf_b[c];
    for (int j = 0; j < 256; j++) nc += sem_b[j] * nf_W[j*256 + c];
    node_const[c] = nc;
    float ec = ef_b[c];
    for (int j = 0; j < 256; j++) ec += ep_b2[j] * ef_W[(256+j)*256 + c];
    for (int j = 0; j < 24;  j++) ec += ea_b[j]  * ef_W[(512+j)*256 + c];
    for (int j = 0; j < 9;   j++) ec += epo_b[j] * ef_W[(768+j)*256 + c];
    edge_const[c] = ec;
}

// ---------------------------------------------------------------------------
// point-cloud encoder, MFMA version.
// u = relu(x@W1f+b1f) -> bf16 LDS [64 x 256] (row stride 264 to dodge bank
// conflicts: 528B = bank step 4 -> 2-way = free). Then U @ W2 via
// mfma_f32_16x16x32_bf16: block tile M=64 x N=256, wave w owns channel group
// [w*64, w*64+64). A-frag: lane = A[m=lane&15][k=(lane>>4)*8+j] (b128 from
// LDS row-major). B-frag: lane = B[k=(lane>>4)*8+j][n=lane&15] (b128 from
// pre-transposed bf16 Wt[n][k]). C/D: col=lane&15, row=(lane>>4)*4+reg.
// Epilogue: relu(acc + b2) -> atomicMax on uint-viewed floats (all >= 0).
// ---------------------------------------------------------------------------
#define USTRIDE 264

__global__ __launch_bounds__(256) void pce_mfma_kernel(
    const float* __restrict__ x, const int* __restrict__ bidx,
    const float* __restrict__ W1f, const float* __restrict__ b1f,
    const unsigned short* __restrict__ Wt, const float* __restrict__ b2,
    float* __restrict__ seg, int P)
{
    __shared__ unsigned short u[64 * USTRIDE];
    __shared__ float xs[64*3];
    __shared__ int nd[64];

    int tid = threadIdx.x;
    int base = blockIdx.x * 64;
    int np = min(64, P - base);

    if (tid < np*3) xs[tid] = x[(size_t)base*3 + tid];
    if (tid < 64) nd[tid] = (tid < np) ? bidx[base + tid] : 0;
    __syncthreads();

    {   // u[p][c] = relu(x@W1f + b1f) as bf16; zero rows for padded points
        int c = tid;
        float w0 = W1f[c], w1 = W1f[256+c], w2 = W1f[512+c], bb = b1f[c];
        for (int p = 0; p < 64; p++) {
            float v = 0.f;
            if (p < np) v = fmaxf(xs[p*3]*w0 + xs[p*3+1]*w1 + xs[p*3+2]*w2 + bb, 0.f);
            u[p*USTRIDE + c] = f32_to_bf16_rne(v);
        }
    }
    __syncthreads();

    int wave  = tid >> 6;
    int lane  = tid & 63;
    int lrow  = lane & 15;
    int lquad = lane >> 4;
    int nbase = wave * 64;

    floatx4 acc[4][4];
    #pragma unroll
    for (int mi = 0; mi < 4; mi++)
        #pragma unroll
        for (int ni = 0; ni < 4; ni++)
            acc[mi][ni] = (floatx4){0.f, 0.f, 0.f, 0.f};

    #pragma unroll
    for (int kc = 0; kc < 8; kc++) {
        int k0 = kc*32 + lquad*8;
        short8 a[4], b[4];
        #pragma unroll
        for (int mi = 0; mi < 4; mi++)
            a[mi] = *(const short8*)&u[(mi*16 + lrow)*USTRIDE + k0];
        #pragma unroll
        for (int ni = 0; ni < 4; ni++)
            b[ni] = *(const short8*)&Wt[(size_t)(nbase + ni*16 + lrow)*256 + k0];
        #pragma unroll
        for (int mi = 0; mi < 4; mi++)
            #pragma unroll
            for (int ni = 0; ni < 4; ni++)
                acc[mi][ni] = __builtin_amdgcn_mfma_f32_16x16x32_bf16(
                                  a[mi], b[ni], acc[mi][ni], 0, 0, 0);
    }

    #pragma unroll
    for (int ni = 0; ni < 4; ni++) {
        int col = nbase + ni*16 + lrow;
        float bias = b2[col];
        #pragma unroll
        for (int mi = 0; mi < 4; mi++) {
            #pragma unroll
            for (int r = 0; r < 4; r++) {
                int m = mi*16 + lquad*4 + r;
                if (m < np) {
                    float y = fmaxf(acc[mi][ni][r] + bias, 0.f);
                    atomicMax((unsigned int*)&seg[(size_t)nd[m]*256 + col],
                              __float_as_uint(y));
                }
            }
        }
    }
}

// ---------------------------------------------------------------------------
// per-wave LN stats over a 256-wide LDS row (2 rows per wave, TN/TE = 8)
// ---------------------------------------------------------------------------
__device__ __forceinline__ void ln_reduce_8rows(const float (*rows)[256], float (*mr)[2],
                                                int tid) {
    int wave = tid >> 6, lane = tid & 63;
    #pragma unroll
    for (int t = 0; t < 2; t++) {
        int n = wave*2 + t;
        float v0 = rows[n][lane], v1 = rows[n][64+lane],
              v2 = rows[n][128+lane], v3 = rows[n][192+lane];
        float s = v0+v1+v2+v3;
        float q = v0*v0+v1*v1+v2*v2+v3*v3;
        for (int off = 32; off > 0; off >>= 1) {
            s += __shfl_down(s, off, 64);
            q += __shfl_down(q, off, 64);
        }
        if (lane == 0) {
            float mean = s * (1.f/256.f);
            float var  = q * (1.f/256.f) - mean*mean;
            mr[n][0] = mean;
            mr[n][1] = rsqrtf(var + LN_EPS);
        }
    }
}

// ---------------------------------------------------------------------------
// nodes: pre = x_sem@sem_comb + h_pos@nf_W[256:512] + h_aff@nf_W[512:768] + node_const
//        out = relu(LN(pre))
// ---------------------------------------------------------------------------
__global__ __launch_bounds__(256) void node_kernel(
    const float* __restrict__ x_sem, const float* __restrict__ h_pos,
    const float* __restrict__ h_aff,
    const float* __restrict__ sem_comb, const float* __restrict__ nf_W,
    const float* __restrict__ node_const,
    const float* __restrict__ ln_g, const float* __restrict__ ln_b,
    float* __restrict__ out, int N)
{
    __shared__ float cat[TN][1024];
    __shared__ float pre[TN][256];
    __shared__ float mr[TN][2];
    int tid = threadIdx.x;
    int base = blockIdx.x * TN;
    int nn = min(TN, N - base);

    for (int i = tid; i < TN*512; i += 256) {
        int n = i >> 9, k = i & 511;
        cat[n][k] = (n < nn) ? x_sem[(size_t)(base+n)*512 + k] : 0.f;
    }
    for (int i = tid; i < TN*256; i += 256) {
        int n = i >> 8, k = i & 255;
        cat[n][512+k] = (n < nn) ? h_pos[(size_t)(base+n)*256 + k] : 0.f;
        cat[n][768+k] = (n < nn) ? h_aff[(size_t)(base+n)*256 + k] : 0.f;
    }
    __syncthreads();

    int c = tid;
    float acc[TN];
    float cst = node_const[c];
    #pragma unroll
    for (int n = 0; n < TN; n++) acc[n] = cst;

    for (int k4 = 0; k4 < 128; k4++) {     // x_sem part, K=512
        int k = k4*4;
        float g0 = sem_comb[(k+0)*256+c], g1 = sem_comb[(k+1)*256+c],
              g2 = sem_comb[(k+2)*256+c], g3 = sem_comb[(k+3)*256+c];
        #pragma unroll
        for (int n = 0; n < TN; n++) {
            float4 uv = *(const float4*)&cat[n][k];
            acc[n] += uv.x*g0 + uv.y*g1 + uv.z*g2 + uv.w*g3;
        }
    }
    const float* Wp = nf_W + 256*256;
    for (int k4 = 0; k4 < 64; k4++) {      // h_pos part
        int k = k4*4;
        float g0 = Wp[(k+0)*256+c], g1 = Wp[(k+1)*256+c],
              g2 = Wp[(k+2)*256+c], g3 = Wp[(k+3)*256+c];
        #pragma unroll
        for (int n = 0; n < TN; n++) {
            float4 uv = *(const float4*)&cat[n][512+k];
            acc[n] += uv.x*g0 + uv.y*g1 + uv.z*g2 + uv.w*g3;
        }
    }
    const float* Wq = nf_W + 512*256;
    for (int k4 = 0; k4 < 64; k4++) {      // h_aff part
        int k = k4*4;
        float g0 = Wq[(k+0)*256+c], g1 = Wq[(k+1)*256+c],
              g2 = Wq[(k+2)*256+c], g3 = Wq[(k+3)*256+c];
        #pragma unroll
        for (int n = 0; n < TN; n++) {
            float4 uv = *(const float4*)&cat[n][768+k];
            acc[n] += uv.x*g0 + uv.y*g1 + uv.z*g2 + uv.w*g3;
        }
    }
    __syncthreads();
    #pragma unroll
    for (int n = 0; n < TN; n++) pre[n][c] = acc[n];
    __syncthreads();
    ln_reduce_8rows(pre, mr, tid);
    __syncthreads();

    float gc = ln_g[c], bc = ln_b[c];
    #pragma unroll
    for (int n = 0; n < TN; n++) {
        if (n < nn) {
            float y = (acc[n] - mr[n][0]) * mr[n][1] * gc + bc;
            out[(size_t)(base+n)*256 + c] = fmaxf(y, 0.f);
        }
    }
}

// ---------------------------------------------------------------------------
// edges: h1 = relu(LN(v@ep_W1+ep_b1)); pre = type_proj[t] + h1@param_comb
//        + anchor@anchor_comb + pose@pose_comb + edge_const; out = relu(LN(pre))
// ---------------------------------------------------------------------------
__global__ __launch_bounds__(256) void edge_kernel(
    const int* __restrict__ etype, const float* __restrict__ eparam,
    const float* __restrict__ eanchor, const float* __restrict__ epose,
    const float* __restrict__ ep_W1, const float* __restrict__ ep_b1,
    const float* __restrict__ ep_ln_g, const float* __restrict__ ep_ln_b,
    const float* __restrict__ type_proj, const float* __restrict__ param_comb,
    const float* __restrict__ anchor_comb, const float* __restrict__ pose_comb,
    const float* __restrict__ edge_const,
    const float* __restrict__ ln_g, const float* __restrict__ ln_b,
    float* __restrict__ out, int E)
{
    __shared__ float h1[TE][256];
    __shared__ float va[TE][5];
    __shared__ float an[TE*24];
    __shared__ float po[TE*9];
    __shared__ int   ty[TE];
    __shared__ float mr[TE][2];
    int tid = threadIdx.x;
    int base = blockIdx.x * TE;
    int ne = min(TE, E - base);

    if (tid < TE) {
        int e = tid;
        if (e < ne) {
            float d  = eparam[(size_t)(base+e)*3 + 0];
            float th = eparam[(size_t)(base+e)*3 + 1];
            float ph = eparam[(size_t)(base+e)*3 + 2];
            va[e][0] = fminf(fmaxf(d*10.f, -5.f), 5.f);
            va[e][1] = __sinf(th); va[e][2] = __cosf(th);
            va[e][3] = __sinf(ph); va[e][4] = __cosf(ph);
            ty[e] = etype[base+e];
        } else {
            va[e][0]=va[e][1]=va[e][2]=va[e][3]=va[e][4]=0.f; ty[e]=0;
        }
    }
    for (int i = tid; i < TE*24; i += 256) an[i] = (i < ne*24) ? eanchor[(size_t)base*24 + i] : 0.f;
    for (int i = tid; i < TE*9;  i += 256) po[i] = (i < ne*9)  ? epose[(size_t)base*9 + i]   : 0.f;
    __syncthreads();

    int c = tid;
    float t[TE];
    {
        float w0=ep_W1[c], w1=ep_W1[256+c], w2=ep_W1[512+c], w3=ep_W1[768+c], w4=ep_W1[1024+c];
        float bb = ep_b1[c];
        #pragma unroll
        for (int e = 0; e < TE; e++) {
            t[e] = va[e][0]*w0 + va[e][1]*w1 + va[e][2]*w2 + va[e][3]*w3 + va[e][4]*w4 + bb;
            h1[e][c] = t[e];
        }
    }
    __syncthreads();
    ln_reduce_8rows(h1, mr, tid);
    __syncthreads();
    {
        float gc = ep_ln_g[c], bc = ep_ln_b[c];
        #pragma unroll
        for (int e = 0; e < TE; e++)
            h1[e][c] = fmaxf((t[e] - mr[e][0]) * mr[e][1] * gc + bc, 0.f);
    }
    __syncthreads();

    float acc[TE];
    float cst = edge_const[c];
    #pragma unroll
    for (int e = 0; e < TE; e++) acc[e] = cst + type_proj[ty[e]*256 + c];

    for (int k4 = 0; k4 < 64; k4++) {
        int k = k4*4;
        float g0 = param_comb[(k+0)*256+c], g1 = param_comb[(k+1)*256+c],
              g2 = param_comb[(k+2)*256+c], g3 = param_comb[(k+3)*256+c];
        #pragma unroll
        for (int e = 0; e < TE; e++) {
            float4 uv = *(const float4*)&h1[e][k];
            acc[e] += uv.x*g0 + uv.y*g1 + uv.z*g2 + uv.w*g3;
        }
    }
    for (int k = 0; k < 24; k++) {
        float g0 = anchor_comb[k*256 + c];
        #pragma unroll
        for (int e = 0; e < TE; e++) acc[e] += an[e*24+k] * g0;
    }
    for (int k = 0; k < 9; k++) {
        float g0 = pose_comb[k*256 + c];
        #pragma unroll
        for (int e = 0; e < TE; e++) acc[e] += po[e*9+k] * g0;
    }
    __syncthreads();
    #pragma unroll
    for (int e = 0; e < TE; e++) h1[e][c] = acc[e];
    __syncthreads();
    ln_reduce_8rows(h1, mr, tid);
    __syncthreads();

    float gc = ln_g[c], bc = ln_b[c];
    #pragma unroll
    for (int e = 0; e < TE; e++) {
        if (e < ne) {
            float y = (acc[e] - mr[e][0]) * mr[e][1] * gc + bc;
            out[(size_t)(base+e)*256 + c] = fmaxf(y, 0.f);
        }
    }
}

// ---------------------------------------------------------------------------
extern "C" void kernel_launch(void* const* d_in, const int* in_sizes, int n_in,
                              void* d_out, int out_size, void* d_ws, size_t ws_size,
                              hipStream_t stream)
{
    const float* x_sem     = (const float*)d_in[0];
    const float* x_pos     = (const float*)d_in[1];
    const int*   pos_bidx  = (const int*)  d_in[2];
    const float* x_aff     = (const float*)d_in[3];
    const int*   aff_bidx  = (const int*)  d_in[4];
    const int*   edge_type = (const int*)  d_in[5];
    const float* edge_param  = (const float*)d_in[6];
    const float* edge_anchor = (const float*)d_in[7];
    const float* edge_pose   = (const float*)d_in[8];
    // d_in[9] = num_nodes (device scalar) — equals N by construction
    const float* sem_W  = (const float*)d_in[10];
    const float* sem_b  = (const float*)d_in[11];
    const float* pos_W1 = (const float*)d_in[12];
    const float* pos_b1 = (const float*)d_in[13];
    const float* pos_bn_g = (const float*)d_in[14];
    const float* pos_bn_b = (const float*)d_in[15];
    const float* pos_W2 = (const float*)d_in[16];
    const float* pos_b2 = (const float*)d_in[17];
    const float* aff_W1 = (const float*)d_in[18];
    const float* aff_b1 = (const float*)d_in[19];
    const float* aff_bn_g = (const float*)d_in[20];
    const float* aff_bn_b = (const float*)d_in[21];
    const float* aff_W2 = (const float*)d_in[22];
    const float* aff_b2 = (const float*)d_in[23];
    const float* nf_W   = (const float*)d_in[24];
    const float* nf_b   = (const float*)d_in[25];
    const float* nf_ln_g = (const float*)d_in[26];
    const float* nf_ln_b = (const float*)d_in[27];
    const float* et_emb = (const float*)d_in[28];
    const float* ep_W1  = (const float*)d_in[29];
    const float* ep_b1  = (const float*)d_in[30];
    const float* ep_ln_g = (const float*)d_in[31];
    const float* ep_ln_b = (const float*)d_in[32];
    const float* ep_W2  = (const float*)d_in[33];
    const float* ep_b2  = (const float*)d_in[34];
    const float* ea_W   = (const float*)d_in[35];
    const float* ea_b   = (const float*)d_in[36];
    const float* epo_W  = (const float*)d_in[37];
    const float* epo_b  = (const float*)d_in[38];
    const float* ef_W   = (const float*)d_in[39];
    const float* ef_b   = (const float*)d_in[40];
    const float* ef_ln_g = (const float*)d_in[41];
    const float* ef_ln_b = (const float*)d_in[42];

    int N = in_sizes[0] / 512;
    int P = in_sizes[1] / 3;
    int E = in_sizes[5];

    float* ws = (float*)d_ws;
    float* h_pos      = ws;                              // N*256
    float* h_aff      = h_pos + (size_t)N*256;           // N*256
    float* stats_pos  = h_aff + (size_t)N*256;           // 16
    float* stats_aff  = stats_pos + 16;                  // 16
    float* pos_W1f    = stats_aff + 16;                  // 768
    float* pos_b1f    = pos_W1f + 768;                   // 256
    float* aff_W1f    = pos_b1f + 256;                   // 768
    float* aff_b1f    = aff_W1f + 768;                   // 256
    float* sem_comb   = aff_b1f + 256;                   // 512*256
    float* param_comb = sem_comb + 512*256;              // 256*256
    float* anchor_comb= param_comb + 256*256;            // 24*256
    float* pose_comb  = anchor_comb + 24*256;            // 9*256
    float* type_proj  = pose_comb + 9*256;               // 7*256
    float* node_const = type_proj + 7*256;               // 256
    float* edge_const = node_const + 256;                // 256
    unsigned short* pos_Wt = (unsigned short*)(edge_const + 256);  // 256*256 bf16
    unsigned short* aff_Wt = pos_Wt + 256*256;                     // 256*256 bf16

    // zero atomicMax targets + stats (ws is poisoned 0xAA before every call)
    hipMemsetAsync(ws, 0, ((size_t)2*N*256 + 32) * sizeof(float), stream);

    stats_kernel<<<512, 256, 0, stream>>>(x_pos, P, stats_pos);
    stats_kernel<<<512, 256, 0, stream>>>(x_aff, P, stats_aff);
    fold_bn_kernel<<<1, 256, 0, stream>>>(stats_pos, pos_W1, pos_b1, pos_bn_g, pos_bn_b,
                                          1.f/(float)P, pos_W1f, pos_b1f);
    fold_bn_kernel<<<1, 256, 0, stream>>>(stats_aff, aff_W1, aff_b1, aff_bn_g, aff_bn_b,
                                          1.f/(float)P, aff_W1f, aff_b1f);
    convert_w2_kernel<<<256, 256, 0, stream>>>(pos_W2, pos_Wt);
    convert_w2_kernel<<<256, 256, 0, stream>>>(aff_W2, aff_Wt);

    small_matmul_kernel<<<512, 256, 0, stream>>>(sem_W,  nf_W,            sem_comb,   256);
    small_matmul_kernel<<<256, 256, 0, stream>>>(ep_W2,  ef_W + 256*256,  param_comb, 256);
    small_matmul_kernel<<<24,  256, 0, stream>>>(ea_W,   ef_W + 512*256,  anchor_comb,256);
    small_matmul_kernel<<<9,   256, 0, stream>>>(epo_W,  ef_W + 768*256,  pose_comb,  256);
    small_matmul_kernel<<<7,   256, 0, stream>>>(et_emb, ef_W,            type_proj,  256);
    consts_kernel<<<1, 256, 0, stream>>>(sem_b, nf_W, nf_b, ep_b2, ea_b, epo_b, ef_W, ef_b,
                                         node_const, edge_const);

    pce_mfma_kernel<<<(P + 63)/64, 256, 0, stream>>>(x_pos, pos_bidx, pos_W1f, pos_b1f,
                                                     pos_Wt, pos_b2, h_pos, P);
    pce_mfma_kernel<<<(P + 63)/64, 256, 0, stream>>>(x_aff, aff_bidx, aff_W1f, aff_b1f,
                                                     aff_Wt, aff_b2, h_aff, P);

    node_kernel<<<(N + TN - 1)/TN, 256, 0, stream>>>(x_sem, h_pos, h_aff, sem_comb, nf_W,
                                                     node_const, nf_ln_g, nf_ln_b,
                                                     (float*)d_out, N);
    edge_kernel<<<(E + TE - 1)/TE, 256, 0, stream>>>(edge_type, edge_param, edge_anchor, edge_pose,
                                                     ep_W1, ep_b1, ep_ln_g, ep_ln_b,
                                                     type_proj, param_comb, anchor_comb, pose_comb,
                                                     edge_const, ef_ln_g, ef_ln_b,
                                                     (float*)d_out + (size_t)N*256, E);
}

// Round 3
// 2617.845 us; speedup vs baseline: 2.1221x; 1.4098x over previous
//
#include <hip/hip_runtime.h>
#include <math.h>

#define LN_EPS 1e-5f

typedef __attribute__((ext_vector_type(8))) short short8;   // 8 bf16 = 4 VGPRs
typedef __attribute__((ext_vector_type(4))) float floatx4;  // MFMA C/D

__device__ __forceinline__ unsigned short f32_to_bf16_rne(float v) {
    unsigned int u = __float_as_uint(v);
    return (unsigned short)((u + 0x7FFFu + ((u >> 16) & 1u)) >> 16);
}

// ---------------------------------------------------------------------------
// stats: sum(x_i), sum(x_i x_j) over rows of (P,3) -> 9 floats (atomicAdd)
// ---------------------------------------------------------------------------
__global__ __launch_bounds__(256) void stats_kernel(const float* __restrict__ x, int P,
                                                    float* __restrict__ stats) {
    int tid = blockIdx.x * blockDim.x + threadIdx.x;
    int stride = gridDim.x * blockDim.x;
    float s[9] = {0.f,0.f,0.f,0.f,0.f,0.f,0.f,0.f,0.f};
    for (int i = tid; i < P; i += stride) {
        float a = x[i*3+0], b = x[i*3+1], c = x[i*3+2];
        s[0]+=a; s[1]+=b; s[2]+=c;
        s[3]+=a*a; s[4]+=a*b; s[5]+=a*c;
        s[6]+=b*b; s[7]+=b*c; s[8]+=c*c;
    }
    #pragma unroll
    for (int j = 0; j < 9; j++) {
        float v = s[j];
        for (int off = 32; off > 0; off >>= 1) v += __shfl_down(v, off, 64);
        if ((threadIdx.x & 63) == 0) atomicAdd(&stats[j], v);
    }
}

// ---------------------------------------------------------------------------
// fold BN into W1/b1:  bn(x@W1+b1) = x@W1f + b1f   (exact: t linear in x)
// ---------------------------------------------------------------------------
__global__ void fold_bn_kernel(const float* __restrict__ stats,
                               const float* __restrict__ W1, const float* __restrict__ b1,
                               const float* __restrict__ g,  const float* __restrict__ b,
                               float Pinv,
                               float* __restrict__ W1f, float* __restrict__ b1f) {
    int c = threadIdx.x;
    float m0 = stats[0]*Pinv, m1 = stats[1]*Pinv, m2 = stats[2]*Pinv;
    float C00 = stats[3]*Pinv - m0*m0;
    float C01 = stats[4]*Pinv - m0*m1;
    float C02 = stats[5]*Pinv - m0*m2;
    float C11 = stats[6]*Pinv - m1*m1;
    float C12 = stats[7]*Pinv - m1*m2;
    float C22 = stats[8]*Pinv - m2*m2;
    float w0 = W1[c], w1 = W1[256+c], w2 = W1[512+c];
    float mean = m0*w0 + m1*w1 + m2*w2 + b1[c];
    float var  = C00*w0*w0 + C11*w1*w1 + C22*w2*w2
               + 2.f*(C01*w0*w1 + C02*w0*w2 + C12*w1*w2);
    float a = g[c] * rsqrtf(var + LN_EPS);
    W1f[c]     = w0*a;
    W1f[256+c] = w1*a;
    W1f[512+c] = w2*a;
    b1f[c] = (b1[c] - mean)*a + b[c];
}

// ---------------------------------------------------------------------------
// transpose + bf16-cast a 256x256 weight: Wt[n][k] = bf16(W[k][n])
// ---------------------------------------------------------------------------
__global__ void convert_w2_kernel(const float* __restrict__ W,
                                  unsigned short* __restrict__ Wt) {
    int n = blockIdx.x, k = threadIdx.x;
    Wt[n*256 + k] = f32_to_bf16_rne(W[k*256 + n]);
}

// ---------------------------------------------------------------------------
// node B: Bt[n][k], k<512: sem_comb[k][n]; 512..767: nf_W[256+j][n]; 768..1023: nf_W[512+j][n]
// ---------------------------------------------------------------------------
__global__ void convert_node_B(const float* __restrict__ sem_comb,
                               const float* __restrict__ nf_W,
                               unsigned short* __restrict__ Bt) {
    int n = blockIdx.x, t = threadIdx.x;
    Bt[n*1024 + t]       = f32_to_bf16_rne(sem_comb[t*256 + n]);
    Bt[n*1024 + 256 + t] = f32_to_bf16_rne(sem_comb[(256 + t)*256 + n]);
    Bt[n*1024 + 512 + t] = f32_to_bf16_rne(nf_W[(256 + t)*256 + n]);
    Bt[n*1024 + 768 + t] = f32_to_bf16_rne(nf_W[(512 + t)*256 + n]);
}

// ---------------------------------------------------------------------------
// edge B: Bt[n][k] (K padded to 320): k<256: param_comb; 256..279: anchor_comb;
// 280..288: pose_comb; 289..319: 0
// ---------------------------------------------------------------------------
__global__ void convert_edge_B(const float* __restrict__ param_comb,
                               const float* __restrict__ anchor_comb,
                               const float* __restrict__ pose_comb,
                               unsigned short* __restrict__ Bt) {
    int n = blockIdx.x, t = threadIdx.x;
    Bt[n*320 + t] = f32_to_bf16_rne(param_comb[t*256 + n]);
    if (t < 64) {
        float v = 0.f;
        if (t < 24)      v = anchor_comb[t*256 + n];
        else if (t < 33) v = pose_comb[(t - 24)*256 + n];
        Bt[n*320 + 256 + t] = f32_to_bf16_rne(v);
    }
}

// ---------------------------------------------------------------------------
// small C[r][c] = sum_j A[r*J+j] * B[j*256+c]   (grid = rows, block = 256)
// ---------------------------------------------------------------------------
__global__ void small_matmul_kernel(const float* __restrict__ A, const float* __restrict__ B,
                                    float* __restrict__ C, int J) {
    int r = blockIdx.x, c = threadIdx.x;
    const float* Ar = A + (size_t)r * J;
    float acc = 0.f;
    for (int j = 0; j < J; j++) acc += Ar[j] * B[j*256 + c];
    C[r*256 + c] = acc;
}

// ---------------------------------------------------------------------------
// constants: node_const = nf_b + sem_b@nf_W[0:256]
//            edge_const = ef_b + ep_b2@ef_W[256:512] + ea_b@ef_W[512:768] + epo_b@ef_W[768:1024]
// ---------------------------------------------------------------------------
__global__ void consts_kernel(const float* __restrict__ sem_b, const float* __restrict__ nf_W,
                              const float* __restrict__ nf_b,
                              const float* __restrict__ ep_b2, const float* __restrict__ ea_b,
                              const float* __restrict__ epo_b, const float* __restrict__ ef_W,
                              const float* __restrict__ ef_b,
                              float* __restrict__ node_const, float* __restrict__ edge_const) {
    int c = threadIdx.x;
    float nc = nf_b[c];
    for (int j = 0; j < 256; j++) nc += sem_b[j] * nf_W[j*256 + c];
    node_const[c] = nc;
    float ec = ef_b[c];
    for (int j = 0; j < 256; j++) ec += ep_b2[j] * ef_W[(256+j)*256 + c];
    for (int j = 0; j < 24;  j++) ec += ea_b[j]  * ef_W[(512+j)*256 + c];
    for (int j = 0; j < 9;   j++) ec += epo_b[j] * ef_W[(768+j)*256 + c];
    edge_const[c] = ec;
}

// ---------------------------------------------------------------------------
// point-cloud encoder, MFMA (validated round 1)
// ---------------------------------------------------------------------------
#define USTRIDE 264

__global__ __launch_bounds__(256) void pce_mfma_kernel(
    const float* __restrict__ x, const int* __restrict__ bidx,
    const float* __restrict__ W1f, const float* __restrict__ b1f,
    const unsigned short* __restrict__ Wt, const float* __restrict__ b2,
    float* __restrict__ seg, int P)
{
    __shared__ unsigned short u[64 * USTRIDE];
    __shared__ float xs[64*3];
    __shared__ int nd[64];

    int tid = threadIdx.x;
    int base = blockIdx.x * 64;
    int np = min(64, P - base);

    if (tid < np*3) xs[tid] = x[(size_t)base*3 + tid];
    if (tid < 64) nd[tid] = (tid < np) ? bidx[base + tid] : 0;
    __syncthreads();

    {
        int c = tid;
        float w0 = W1f[c], w1 = W1f[256+c], w2 = W1f[512+c], bb = b1f[c];
        for (int p = 0; p < 64; p++) {
            float v = 0.f;
            if (p < np) v = fmaxf(xs[p*3]*w0 + xs[p*3+1]*w1 + xs[p*3+2]*w2 + bb, 0.f);
            u[p*USTRIDE + c] = f32_to_bf16_rne(v);
        }
    }
    __syncthreads();

    int wave  = tid >> 6;
    int lane  = tid & 63;
    int lrow  = lane & 15;
    int lquad = lane >> 4;
    int nbase = wave * 64;

    floatx4 acc[4][4];
    #pragma unroll
    for (int mi = 0; mi < 4; mi++)
        #pragma unroll
        for (int ni = 0; ni < 4; ni++)
            acc[mi][ni] = (floatx4){0.f, 0.f, 0.f, 0.f};

    #pragma unroll
    for (int kc = 0; kc < 8; kc++) {
        int k0 = kc*32 + lquad*8;
        short8 a[4], b[4];
        #pragma unroll
        for (int mi = 0; mi < 4; mi++)
            a[mi] = *(const short8*)&u[(mi*16 + lrow)*USTRIDE + k0];
        #pragma unroll
        for (int ni = 0; ni < 4; ni++)
            b[ni] = *(const short8*)&Wt[(size_t)(nbase + ni*16 + lrow)*256 + k0];
        #pragma unroll
        for (int mi = 0; mi < 4; mi++)
            #pragma unroll
            for (int ni = 0; ni < 4; ni++)
                acc[mi][ni] = __builtin_amdgcn_mfma_f32_16x16x32_bf16(
                                  a[mi], b[ni], acc[mi][ni], 0, 0, 0);
    }

    #pragma unroll
    for (int ni = 0; ni < 4; ni++) {
        int col = nbase + ni*16 + lrow;
        float bias = b2[col];
        #pragma unroll
        for (int mi = 0; mi < 4; mi++) {
            #pragma unroll
            for (int r = 0; r < 4; r++) {
                int m = mi*16 + lquad*4 + r;
                if (m < np) {
                    float y = fmaxf(acc[mi][ni][r] + bias, 0.f);
                    atomicMax((unsigned int*)&seg[(size_t)nd[m]*256 + col],
                              __float_as_uint(y));
                }
            }
        }
    }
}

// ---------------------------------------------------------------------------
// LN reduce helpers: rows of 256 fp32 in LDS (given stride), write mean/rstd
// ---------------------------------------------------------------------------
__device__ __forceinline__ void ln_reduce_rows16(const float* __restrict__ rows, int stride,
                                                 float (*mr)[2], int tid) {
    int wave = tid >> 6, lane = tid & 63;
    for (int t = 0; t < 16; t++) {
        int n = wave*16 + t;
        const float* r = rows + n*stride;
        float v0 = r[lane], v1 = r[64+lane], v2 = r[128+lane], v3 = r[192+lane];
        float s = v0+v1+v2+v3;
        float q = v0*v0+v1*v1+v2*v2+v3*v3;
        for (int off = 32; off > 0; off >>= 1) {
            s += __shfl_down(s, off, 64);
            q += __shfl_down(q, off, 64);
        }
        if (lane == 0) {
            float mean = s * (1.f/256.f);
            mr[n][0] = mean;
            mr[n][1] = rsqrtf(q * (1.f/256.f) - mean*mean + LN_EPS);
        }
    }
}

__device__ __forceinline__ void ln_reduce_rows2(const float* __restrict__ rows, int stride,
                                                float (*mr)[2], int tid) {
    int wave = tid >> 6, lane = tid & 63;
    #pragma unroll
    for (int t = 0; t < 2; t++) {
        int n = wave*2 + t;
        const float* r = rows + n*stride;
        float v0 = r[lane], v1 = r[64+lane], v2 = r[128+lane], v3 = r[192+lane];
        float s = v0+v1+v2+v3;
        float q = v0*v0+v1*v1+v2*v2+v3*v3;
        for (int off = 32; off > 0; off >>= 1) {
            s += __shfl_down(s, off, 64);
            q += __shfl_down(q, off, 64);
        }
        if (lane == 0) {
            float mean = s * (1.f/256.f);
            mr[n][0] = mean;
            mr[n][1] = rsqrtf(q * (1.f/256.f) - mean*mean + LN_EPS);
        }
    }
}

// ---------------------------------------------------------------------------
// node MFMA: 64 nodes/block. A = [x_sem | h_pos | h_aff] bf16, K=1024 in 4
// chunks of 256 staged through LDS (stride 264). B = BtN[n][k] bf16 (L2).
// Epilogue: +node_const -> LDS fp32 (stride 260) -> LN -> relu -> out.
// LDS: union(A-chunk 33 KB, pre 66.5 KB) = 66.5 KB -> 2 blocks/CU.
// ---------------------------------------------------------------------------
#define NA_STRIDE 264
#define NP_STRIDE 260

__global__ __launch_bounds__(256) void node_mfma_kernel(
    const float* __restrict__ x_sem, const float* __restrict__ h_pos,
    const float* __restrict__ h_aff,
    const unsigned short* __restrict__ BtN,
    const float* __restrict__ node_const,
    const float* __restrict__ ln_g, const float* __restrict__ ln_b,
    float* __restrict__ out, int N)
{
    __shared__ __align__(16) float smem[64 * NP_STRIDE];  // union: A chunk / pre
    unsigned short* As = (unsigned short*)smem;
    float* pre = smem;
    __shared__ float mr[64][2];

    int tid = threadIdx.x;
    int base = blockIdx.x * 64;
    int nn = min(64, N - base);

    int wave  = tid >> 6;
    int lane  = tid & 63;
    int lrow  = lane & 15;
    int lquad = lane >> 4;
    int nbase = wave * 64;

    floatx4 acc[4][4];
    #pragma unroll
    for (int mi = 0; mi < 4; mi++)
        #pragma unroll
        for (int ni = 0; ni < 4; ni++)
            acc[mi][ni] = (floatx4){0.f, 0.f, 0.f, 0.f};

    #pragma unroll
    for (int chunk = 0; chunk < 4; chunk++) {
        const float* src; int sstride;
        if (chunk == 0)      { src = x_sem + (size_t)base*512;       sstride = 512; }
        else if (chunk == 1) { src = x_sem + (size_t)base*512 + 256; sstride = 512; }
        else if (chunk == 2) { src = h_pos + (size_t)base*256;       sstride = 256; }
        else                 { src = h_aff + (size_t)base*256;       sstride = 256; }

        for (int i = tid; i < 64*64; i += 256) {
            int row = i >> 6, c4 = (i & 63) * 4;
            float4 v = {0.f, 0.f, 0.f, 0.f};
            if (row < nn) v = *(const float4*)&src[(size_t)row*sstride + c4];
            ushort4 h;
            h.x = f32_to_bf16_rne(v.x); h.y = f32_to_bf16_rne(v.y);
            h.z = f32_to_bf16_rne(v.z); h.w = f32_to_bf16_rne(v.w);
            *(ushort4*)&As[row*NA_STRIDE + c4] = h;
        }
        __syncthreads();

        #pragma unroll
        for (int kc = 0; kc < 8; kc++) {
            int k0 = kc*32 + lquad*8;
            short8 a[4], b[4];
            #pragma unroll
            for (int mi = 0; mi < 4; mi++)
                a[mi] = *(const short8*)&As[(mi*16 + lrow)*NA_STRIDE + k0];
            #pragma unroll
            for (int ni = 0; ni < 4; ni++)
                b[ni] = *(const short8*)&BtN[(size_t)(nbase + ni*16 + lrow)*1024
                                             + chunk*256 + k0];
            #pragma unroll
            for (int mi = 0; mi < 4; mi++)
                #pragma unroll
                for (int ni = 0; ni < 4; ni++)
                    acc[mi][ni] = __builtin_amdgcn_mfma_f32_16x16x32_bf16(
                                      a[mi], b[ni], acc[mi][ni], 0, 0, 0);
        }
        __syncthreads();   // before next chunk (or pre-write) reuses smem
    }

    // epilogue: pre = acc + node_const
    #pragma unroll
    for (int ni = 0; ni < 4; ni++) {
        int col = nbase + ni*16 + lrow;
        float cst = node_const[col];
        #pragma unroll
        for (int mi = 0; mi < 4; mi++)
            #pragma unroll
            for (int r = 0; r < 4; r++) {
                int m = mi*16 + lquad*4 + r;
                pre[m*NP_STRIDE + col] = acc[mi][ni][r] + cst;
            }
    }
    __syncthreads();
    ln_reduce_rows16(pre, NP_STRIDE, mr, tid);
    __syncthreads();

    float gc = ln_g[tid], bc = ln_b[tid];
    for (int m = 0; m < 64; m++) {
        if (m < nn) {
            float y = (pre[m*NP_STRIDE + tid] - mr[m][0]) * mr[m][1] * gc + bc;
            out[(size_t)(base + m)*256 + tid] = fmaxf(y, 0.f);
        }
    }
}

// ---------------------------------------------------------------------------
// edge MFMA: 64 edges/block. h1 = relu(LN(v@ep_W1+b1)) computed in 8 groups
// of 8 rows into A bf16 [64 x 320] (cols 256..288 = anchor|pose, 289.. = 0).
// MFMA K=320 vs BtE. Epilogue: + type_proj[ty] + edge_const -> LN -> relu.
// LDS: union(A 42 KB / pre 66.5 KB, h1tmp at +48K) + va/ty/mr ~ 69 KB.
// ---------------------------------------------------------------------------
#define EA_STRIDE 328
#define EP_STRIDE 260

__global__ __launch_bounds__(256) void edge_mfma_kernel(
    const int* __restrict__ etype, const float* __restrict__ eparam,
    const float* __restrict__ eanchor, const float* __restrict__ epose,
    const float* __restrict__ ep_W1, const float* __restrict__ ep_b1,
    const float* __restrict__ ep_ln_g, const float* __restrict__ ep_ln_b,
    const unsigned short* __restrict__ BtE,
    const float* __restrict__ type_proj, const float* __restrict__ edge_const,
    const float* __restrict__ ln_g, const float* __restrict__ ln_b,
    float* __restrict__ out, int E)
{
    __shared__ __align__(16) float smem[64 * EP_STRIDE];   // union
    unsigned short* As = (unsigned short*)smem;            // 64*328*2 = 41984 B
    float* pre = smem;                                     // 64*260*4 = 66560 B
    float* h1tmp = smem + 12288;                           // 49152 B offset; 8*260*4 = 8320 B
    __shared__ float va[64][5];
    __shared__ int   ty[64];
    __shared__ float mr[64][2];
    __shared__ float mr8[8][2];

    int tid = threadIdx.x;
    int base = blockIdx.x * 64;
    int ne = min(64, E - base);

    // zero A tile (covers the pad columns); compute va/ty
    for (int i = tid; i < 64*EA_STRIDE/4; i += 256)
        ((ushort4*)As)[i] = (ushort4){0, 0, 0, 0};
    if (tid < 64) {
        int e = tid;
        if (e < ne) {
            float d  = eparam[(size_t)(base+e)*3 + 0];
            float th = eparam[(size_t)(base+e)*3 + 1];
            float ph = eparam[(size_t)(base+e)*3 + 2];
            va[e][0] = fminf(fmaxf(d*10.f, -5.f), 5.f);
            va[e][1] = __sinf(th); va[e][2] = __cosf(th);
            va[e][3] = __sinf(ph); va[e][4] = __cosf(ph);
            ty[e] = etype[base+e];
        } else {
            va[e][0]=va[e][1]=va[e][2]=va[e][3]=va[e][4]=0.f; ty[e]=0;
        }
    }
    __syncthreads();

    // anchor/pose into A cols 256..288
    for (int i = tid; i < 64*24; i += 256) {
        float v = (i < ne*24) ? eanchor[(size_t)base*24 + i] : 0.f;
        As[(i/24)*EA_STRIDE + 256 + (i % 24)] = f32_to_bf16_rne(v);
    }
    for (int i = tid; i < 64*9; i += 256) {
        float v = (i < ne*9) ? epose[(size_t)base*9 + i] : 0.f;
        As[(i/9)*EA_STRIDE + 280 + (i % 9)] = f32_to_bf16_rne(v);
    }

    // h1 rows in 8 groups of 8
    int c = tid;
    float w0=ep_W1[c], w1=ep_W1[256+c], w2=ep_W1[512+c], w3=ep_W1[768+c], w4=ep_W1[1024+c];
    float bb = ep_b1[c];
    float gc1 = ep_ln_g[c], bc1 = ep_ln_b[c];
    for (int g = 0; g < 8; g++) {
        float t[8];
        #pragma unroll
        for (int e = 0; e < 8; e++) {
            int ge = g*8 + e;
            t[e] = va[ge][0]*w0 + va[ge][1]*w1 + va[ge][2]*w2 + va[ge][3]*w3
                 + va[ge][4]*w4 + bb;
            h1tmp[e*EP_STRIDE + c] = t[e];
        }
        __syncthreads();
        ln_reduce_rows2(h1tmp, EP_STRIDE, mr8, tid);
        __syncthreads();
        #pragma unroll
        for (int e = 0; e < 8; e++) {
            float y = fmaxf((t[e] - mr8[e][0]) * mr8[e][1] * gc1 + bc1, 0.f);
            As[(g*8 + e)*EA_STRIDE + c] = f32_to_bf16_rne(y);
        }
        __syncthreads();
    }

    int wave  = tid >> 6;
    int lane  = tid & 63;
    int lrow  = lane & 15;
    int lquad = lane >> 4;
    int nbase = wave * 64;

    floatx4 acc[4][4];
    #pragma unroll
    for (int mi = 0; mi < 4; mi++)
        #pragma unroll
        for (int ni = 0; ni < 4; ni++)
            acc[mi][ni] = (floatx4){0.f, 0.f, 0.f, 0.f};

    #pragma unroll
    for (int kc = 0; kc < 10; kc++) {
        int k0 = kc*32 + lquad*8;
        short8 a[4], b[4];
        #pragma unroll
        for (int mi = 0; mi < 4; mi++)
            a[mi] = *(const short8*)&As[(mi*16 + lrow)*EA_STRIDE + k0];
        #pragma unroll
        for (int ni = 0; ni < 4; ni++)
            b[ni] = *(const short8*)&BtE[(size_t)(nbase + ni*16 + lrow)*320 + k0];
        #pragma unroll
        for (int mi = 0; mi < 4; mi++)
            #pragma unroll
            for (int ni = 0; ni < 4; ni++)
                acc[mi][ni] = __builtin_amdgcn_mfma_f32_16x16x32_bf16(
                                  a[mi], b[ni], acc[mi][ni], 0, 0, 0);
    }
    __syncthreads();   // done reading As; smem becomes pre

    #pragma unroll
    for (int ni = 0; ni < 4; ni++) {
        int col = nbase + ni*16 + lrow;
        float cst = edge_const[col];
        #pragma unroll
        for (int mi = 0; mi < 4; mi++)
            #pragma unroll
            for (int r = 0; r < 4; r++) {
                int m = mi*16 + lquad*4 + r;
                pre[m*EP_STRIDE + col] = acc[mi][ni][r] + cst
                                       + type_proj[ty[m]*256 + col];
            }
    }
    __syncthreads();
    ln_reduce_rows16(pre, EP_STRIDE, mr, tid);
    __syncthreads();

    float gc = ln_g[tid], bc = ln_b[tid];
    for (int m = 0; m < 64; m++) {
        if (m < ne) {
            float y = (pre[m*EP_STRIDE + tid] - mr[m][0]) * mr[m][1] * gc + bc;
            out[(size_t)(base + m)*256 + tid] = fmaxf(y, 0.f);
        }
    }
}

// ---------------------------------------------------------------------------
extern "C" void kernel_launch(void* const* d_in, const int* in_sizes, int n_in,
                              void* d_out, int out_size, void* d_ws, size_t ws_size,
                              hipStream_t stream)
{
    const float* x_sem     = (const float*)d_in[0];
    const float* x_pos     = (const float*)d_in[1];
    const int*   pos_bidx  = (const int*)  d_in[2];
    const float* x_aff     = (const float*)d_in[3];
    const int*   aff_bidx  = (const int*)  d_in[4];
    const int*   edge_type = (const int*)  d_in[5];
    const float* edge_param  = (const float*)d_in[6];
    const float* edge_anchor = (const float*)d_in[7];
    const float* edge_pose   = (const float*)d_in[8];
    const float* sem_W  = (const float*)d_in[10];
    const float* sem_b  = (const float*)d_in[11];
    const float* pos_W1 = (const float*)d_in[12];
    const float* pos_b1 = (const float*)d_in[13];
    const float* pos_bn_g = (const float*)d_in[14];
    const float* pos_bn_b = (const float*)d_in[15];
    const float* pos_W2 = (const float*)d_in[16];
    const float* pos_b2 = (const float*)d_in[17];
    const float* aff_W1 = (const float*)d_in[18];
    const float* aff_b1 = (const float*)d_in[19];
    const float* aff_bn_g = (const float*)d_in[20];
    const float* aff_bn_b = (const float*)d_in[21];
    const float* aff_W2 = (const float*)d_in[22];
    const float* aff_b2 = (const float*)d_in[23];
    const float* nf_W   = (const float*)d_in[24];
    const float* nf_b   = (const float*)d_in[25];
    const float* nf_ln_g = (const float*)d_in[26];
    const float* nf_ln_b = (const float*)d_in[27];
    const float* et_emb = (const float*)d_in[28];
    const float* ep_W1  = (const float*)d_in[29];
    const float* ep_b1  = (const float*)d_in[30];
    const float* ep_ln_g = (const float*)d_in[31];
    const float* ep_ln_b = (const float*)d_in[32];
    const float* ep_W2  = (const float*)d_in[33];
    const float* ep_b2  = (const float*)d_in[34];
    const float* ea_W   = (const float*)d_in[35];
    const float* ea_b   = (const float*)d_in[36];
    const float* epo_W  = (const float*)d_in[37];
    const float* epo_b  = (const float*)d_in[38];
    const float* ef_W   = (const float*)d_in[39];
    const float* ef_b   = (const float*)d_in[40];
    const float* ef_ln_g = (const float*)d_in[41];
    const float* ef_ln_b = (const float*)d_in[42];

    int N = in_sizes[0] / 512;
    int P = in_sizes[1] / 3;
    int E = in_sizes[5];

    float* ws = (float*)d_ws;
    float* h_pos      = ws;                              // N*256
    float* h_aff      = h_pos + (size_t)N*256;           // N*256
    float* stats_pos  = h_aff + (size_t)N*256;           // 16
    float* stats_aff  = stats_pos + 16;                  // 16
    float* pos_W1f    = stats_aff + 16;                  // 768
    float* pos_b1f    = pos_W1f + 768;                   // 256
    float* aff_W1f    = pos_b1f + 256;                   // 768
    float* aff_b1f    = aff_W1f + 768;                   // 256
    float* sem_comb   = aff_b1f + 256;                   // 512*256
    float* param_comb = sem_comb + 512*256;              // 256*256
    float* anchor_comb= param_comb + 256*256;            // 24*256
    float* pose_comb  = anchor_comb + 24*256;            // 9*256
    float* type_proj  = pose_comb + 9*256;               // 7*256
    float* node_const = type_proj + 7*256;               // 256
    float* edge_const = node_const + 256;                // 256
    unsigned short* pos_Wt = (unsigned short*)(edge_const + 256);  // 256*256 bf16
    unsigned short* aff_Wt = pos_Wt + 256*256;                     // 256*256 bf16
    unsigned short* BtN    = aff_Wt + 256*256;                     // 256*1024 bf16
    unsigned short* BtE    = BtN + 256*1024;                       // 256*320 bf16

    // zero atomicMax targets + stats (ws is poisoned 0xAA before every call)
    hipMemsetAsync(ws, 0, ((size_t)2*N*256 + 32) * sizeof(float), stream);

    stats_kernel<<<512, 256, 0, stream>>>(x_pos, P, stats_pos);
    stats_kernel<<<512, 256, 0, stream>>>(x_aff, P, stats_aff);
    fold_bn_kernel<<<1, 256, 0, stream>>>(stats_pos, pos_W1, pos_b1, pos_bn_g, pos_bn_b,
                                          1.f/(float)P, pos_W1f, pos_b1f);
    fold_bn_kernel<<<1, 256, 0, stream>>>(stats_aff, aff_W1, aff_b1, aff_bn_g, aff_bn_b,
                                          1.f/(float)P, aff_W1f, aff_b1f);
    convert_w2_kernel<<<256, 256, 0, stream>>>(pos_W2, pos_Wt);
    convert_w2_kernel<<<256, 256, 0, stream>>>(aff_W2, aff_Wt);

    small_matmul_kernel<<<512, 256, 0, stream>>>(sem_W,  nf_W,            sem_comb,   256);
    small_matmul_kernel<<<256, 256, 0, stream>>>(ep_W2,  ef_W + 256*256,  param_comb, 256);
    small_matmul_kernel<<<24,  256, 0, stream>>>(ea_W,   ef_W + 512*256,  anchor_comb,256);
    small_matmul_kernel<<<9,   256, 0, stream>>>(epo_W,  ef_W + 768*256,  pose_comb,  256);
    small_matmul_kernel<<<7,   256, 0, stream>>>(et_emb, ef_W,            type_proj,  256);
    consts_kernel<<<1, 256, 0, stream>>>(sem_b, nf_W, nf_b, ep_b2, ea_b, epo_b, ef_W, ef_b,
                                         node_const, edge_const);
    convert_node_B<<<256, 256, 0, stream>>>(sem_comb, nf_W, BtN);
    convert_edge_B<<<256, 256, 0, stream>>>(param_comb, anchor_comb, pose_comb, BtE);

    pce_mfma_kernel<<<(P + 63)/64, 256, 0, stream>>>(x_pos, pos_bidx, pos_W1f, pos_b1f,
                                                     pos_Wt, pos_b2, h_pos, P);
    pce_mfma_kernel<<<(P + 63)/64, 256, 0, stream>>>(x_aff, aff_bidx, aff_W1f, aff_b1f,
                                                     aff_Wt, aff_b2, h_aff, P);

    node_mfma_kernel<<<(N + 63)/64, 256, 0, stream>>>(x_sem, h_pos, h_aff, BtN, node_const,
                                                      nf_ln_g, nf_ln_b,
                                                      (float*)d_out, N);
    edge_mfma_kernel<<<(E + 63)/64, 256, 0, stream>>>(edge_type, edge_param, edge_anchor,
                                                      edge_pose, ep_W1, ep_b1,
                                                      ep_ln_g, ep_ln_b, BtE,
                                                      type_proj, edge_const,
                                                      ef_ln_g, ef_ln_b,
                                                      (float*)d_out + (size_t)N*256, E);
}